// Round 14
// baseline (511.334 us; speedup 1.0000x reference)
//
#include <hip/hip_runtime.h>

typedef unsigned short u16;
typedef unsigned int u32;
typedef float f32x4 __attribute__((ext_vector_type(4)));
typedef __bf16 bf16x8 __attribute__((ext_vector_type(8)));
typedef unsigned short u16x8 __attribute__((ext_vector_type(8)));

#define L_SEQ 2048
#define DMODEL 2048
#define DINNER 2048
#define DXB 512
#define NHEADS 32
#define DPROJ 5152   // 2*DINNER + 2*DXB + NHEADS
#define DPROJ_PAD 5376  // 21 * 256
#define CONVCH 3072  // 2*DXB + DINNER
#define DFF 8192
#define NCHUNK 32
#define CHUNK 64

__device__ __forceinline__ float bf2f(u16 u) {
  union { unsigned int i; float f; } v; v.i = ((unsigned int)u) << 16; return v.f;
}
__device__ __forceinline__ u16 f2bf(float f) {
  union { float f; unsigned int i; } v; v.f = f;
  unsigned int u = v.i;
  u += 0x7FFFu + ((u >> 16) & 1u);
  return (u16)(u >> 16);
}
__device__ __forceinline__ float siluf(float x) { return x / (1.f + __expf(-x)); }

#define GL16(gsrc, ldst) \
  __builtin_amdgcn_global_load_lds((const __attribute__((address_space(1))) u32*)(gsrc), \
                                   (__attribute__((address_space(3))) u32*)(ldst), 16, 0, 0)
#define SBAR() __builtin_amdgcn_s_barrier()
#define WAIT_VM4() asm volatile("s_waitcnt vmcnt(4)" ::: "memory")
#define WAIT_VM0() asm volatile("s_waitcnt vmcnt(0)" ::: "memory")

// ---------------------------------------------------------------------------
// fp32 -> bf16 weight conversion (standalone; fused-in-GEMM REJECTED round 10)
// ---------------------------------------------------------------------------
__global__ __launch_bounds__(256) void cvt_k(
    const float* __restrict__ s, u16* __restrict__ d, int n8)
{
  const int i = blockIdx.x * 256 + threadIdx.x;
  if (i >= n8) return;
  f32x4 a = *(const f32x4*)(s + (size_t)i * 8);
  f32x4 b = *(const f32x4*)(s + (size_t)i * 8 + 4);
  u16x8 o;
#pragma unroll
  for (int j = 0; j < 4; ++j) { o[j] = f2bf(a[j]); o[j + 4] = f2bf(b[j]); }
  *(u16x8*)(d + (size_t)i * 8) = o;
}

// in_proj variant: pad rows [DPROJ, DPROJ_PAD) with zeros
__global__ __launch_bounds__(256) void cvt_pad_k(
    const float* __restrict__ s, u16* __restrict__ d)
{
  const int i = blockIdx.x * 256 + threadIdx.x;  // over DPROJ_PAD*2048/8
  const int row = (i * 8) >> 11;
  u16x8 o;
  if (row < DPROJ) {
    f32x4 a = *(const f32x4*)(s + (size_t)i * 8);
    f32x4 b = *(const f32x4*)(s + (size_t)i * 8 + 4);
#pragma unroll
    for (int j = 0; j < 4; ++j) { o[j] = f2bf(a[j]); o[j + 4] = f2bf(b[j]); }
  } else {
#pragma unroll
    for (int j = 0; j < 8; ++j) o[j] = 0;
  }
  *(u16x8*)(d + (size_t)i * 8) = o;
}

// ---------------------------------------------------------------------------
// 256x256 8-phase GEMM (round-7/11 config — validated local optimum ~860 TF;
// 8 FINE phases are load-bearing: wave role-diversity for the CU scheduler;
// merged-phase variant regressed 28%). Compiler-scheduled lgkm, ONE barrier
// per phase, counted vmcnt(4) at ph4/ph8 (T4), setprio (T5), pre-swizzled
// gload + XOR ds_read (T2), XCD-bijective chunk + column-major decode (T1).
// EPI 0: bf16 out. EPI 2: BF16 split-K partial (round 14 — halves partial
// traffic; bf16 rounding of K=512..1024 partials ~0.002 abs, safe).
// EPI 3: silu(gateB)*acc -> bf16.
// ---------------------------------------------------------------------------
template<int MH, int NH>
__device__ __forceinline__ void mfma16(f32x4 (&acc)[8][4], const bf16x8 (&af)[4][2],
                                       const bf16x8 (&bfq)[2][2][2]) {
#pragma unroll
  for (int s = 0; s < 2; ++s)
#pragma unroll
    for (int m = 0; m < 4; ++m)
#pragma unroll
      for (int n = 0; n < 2; ++n)
        acc[MH * 4 + m][NH * 2 + n] = __builtin_amdgcn_mfma_f32_16x16x32_bf16(
            af[m][s], bfq[NH][n][s], acc[MH * 4 + m][NH * 2 + n], 0, 0, 0);
}

template<int EPI, int SPLIT>
__global__ __launch_bounds__(512, 2) void gemm8(
    const u16* __restrict__ A, const u16* __restrict__ W,
    void* __restrict__ Cptr, const u16* __restrict__ gateB,
    const int N, const int K, const int gx)
{
  __shared__ u16 sm[65536];  // 128 KiB: [buf<<15] + [A:0 | B:16384] + row*64
  const int tid = threadIdx.x;
  const int wid = tid >> 6, ln = tid & 63;
  const int wm = wid >> 2, wn = wid & 3;

  const int nwg = gridDim.x;
  int wg = (int)blockIdx.x;
  wg = (wg & 7) * (nwg >> 3) + (wg >> 3);
  const int tilesPerZ = gx << 3;
  const int bz = wg / tilesPerZ;
  const int rem = wg - bz * tilesPerZ;
  const int bx = rem >> 3;
  const int by = rem & 7;
  const int m0 = by << 8, n0 = bx << 8;
  const int NT = (K >> 6) / SPLIT;
  const int ktB = bz * NT;

  f32x4 acc[8][4];
#pragma unroll
  for (int i = 0; i < 8; ++i)
#pragma unroll
    for (int j = 0; j < 4; ++j) acc[i][j] = f32x4{0.f, 0.f, 0.f, 0.f};

  const int l8r = ln >> 3;                 // 0..7
  const int schunk = (ln & 7) ^ l8r;       // pre-swizzled source chunk
  const int lr16 = ln & 15;
  const int q4 = ln >> 4;
  const int swz = ln & 7;
  const int c0 = ((q4 ^ swz) << 3);        // u16 offset of k-slice 0 chunk

  auto stageA = [&](int buf, int kt, int h) {
#pragma unroll
    for (int g = 0; g < 2; ++g) {
      const int rr = (wid << 3) + l8r;
      const size_t grow = (size_t)(m0 + (g << 7) + (h << 6) + rr);
      const u16* src = A + grow * K + (size_t)((ktB + kt) << 6) + (schunk << 3);
      u16* dst = &sm[(buf << 15) + (((h << 7) + (g << 6) + (wid << 3)) << 6)];
      GL16(src, dst);
    }
  };
  auto stageB = [&](int buf, int kt, int h) {
#pragma unroll
    for (int g = 0; g < 2; ++g) {
      const int v = (g << 6) + (wid << 3) + l8r;
      const int grow = n0 + ((v >> 5) << 6) + (h << 5) + (v & 31);
      const u16* src = W + (size_t)grow * K + (size_t)((ktB + kt) << 6) + (schunk << 3);
      u16* dst = &sm[(buf << 15) + 16384 + (((h << 7) + (g << 6) + (wid << 3)) << 6)];
      GL16(src, dst);
    }
  };

  bf16x8 af[4][2], bfq[2][2][2];
  auto loadA = [&](int buf, int mh) {
#pragma unroll
    for (int m = 0; m < 4; ++m) {
      const int lrA = (mh << 7) + (wm << 6) + (m << 4) + lr16;
      const u16* p = &sm[(buf << 15) + (lrA << 6)];
      af[m][0] = *(const bf16x8*)(p + c0);
      af[m][1] = *(const bf16x8*)(p + (c0 ^ 32));
    }
  };
  auto loadB = [&](int buf, int nh) {
#pragma unroll
    for (int n = 0; n < 2; ++n) {
      const int lrB = (nh << 7) + (wn << 5) + (n << 4) + lr16;
      const u16* p = &sm[(buf << 15) + 16384 + (lrB << 6)];
      bfq[nh][n][0] = *(const bf16x8*)(p + c0);
      bfq[nh][n][1] = *(const bf16x8*)(p + (c0 ^ 32));
    }
  };

  // Prologue: kt0 full (8 loads) + kt1 {A-h0, B-h1} (4 loads); wait kt0.
  stageA(0, 0, 0); stageA(0, 0, 1); stageB(0, 0, 0); stageB(0, 0, 1);
  stageA(1, 1, 0); stageB(1, 1, 1);
  WAIT_VM4();
  SBAR();

  for (int kt = 0; kt < NT; kt += 2) {
    const bool s2 = (kt + 2) < NT, s3 = (kt + 3) < NT;
    // ph1: buf0 quad(0,0)
    loadA(0, 0); loadB(0, 0);
    stageA(1, kt + 1, 1);
    __builtin_amdgcn_s_setprio(1); mfma16<0, 0>(acc, af, bfq); __builtin_amdgcn_s_setprio(0);
    SBAR();
    // ph2: quad(0,1)
    loadB(0, 1);
    stageB(1, kt + 1, 0);
    __builtin_amdgcn_s_setprio(1); mfma16<0, 1>(acc, af, bfq); __builtin_amdgcn_s_setprio(0);
    SBAR();
    // ph3: quad(1,1)
    loadA(0, 1);
    if (s2) stageA(0, kt + 2, 0);
    __builtin_amdgcn_s_setprio(1); mfma16<1, 1>(acc, af, bfq); __builtin_amdgcn_s_setprio(0);
    SBAR();
    // ph4: quad(1,0) pure-MFMA; counted vmcnt before switching to buf1
    if (s2) stageB(0, kt + 2, 1);
    __builtin_amdgcn_s_setprio(1); mfma16<1, 0>(acc, af, bfq); __builtin_amdgcn_s_setprio(0);
    if (s2) { WAIT_VM4(); } else { WAIT_VM0(); }
    SBAR();
    // ph5: buf1 quad(0,0)
    loadA(1, 0); loadB(1, 0);
    if (s2) stageA(0, kt + 2, 1);
    __builtin_amdgcn_s_setprio(1); mfma16<0, 0>(acc, af, bfq); __builtin_amdgcn_s_setprio(0);
    SBAR();
    // ph6: quad(0,1)
    loadB(1, 1);
    if (s2) stageB(0, kt + 2, 0);
    __builtin_amdgcn_s_setprio(1); mfma16<0, 1>(acc, af, bfq); __builtin_amdgcn_s_setprio(0);
    SBAR();
    // ph7: quad(1,1)
    loadA(1, 1);
    if (s3) stageA(1, kt + 3, 0);
    __builtin_amdgcn_s_setprio(1); mfma16<1, 1>(acc, af, bfq); __builtin_amdgcn_s_setprio(0);
    SBAR();
    // ph8: quad(1,0) pure-MFMA; counted vmcnt before next iter reads buf0
    if (s3) stageB(1, kt + 3, 1);
    __builtin_amdgcn_s_setprio(1); mfma16<1, 0>(acc, af, bfq); __builtin_amdgcn_s_setprio(0);
    if (s2) { if (s3) { WAIT_VM4(); } else { WAIT_VM0(); } }
    SBAR();
  }

  // Epilogue: C/D layout col=ln&15, row=(ln>>4)*4+j (m89)
  const int crow0 = m0 + (wm << 7) + (q4 << 2);
  const int ccol0 = n0 + (wn << 6) + lr16;
#pragma unroll
  for (int M = 0; M < 8; ++M) {
#pragma unroll
    for (int n = 0; n < 4; ++n) {
      const int col = ccol0 + (n << 4);
      if (col < N) {
#pragma unroll
        for (int j = 0; j < 4; ++j) {
          const size_t idx = (size_t)(crow0 + (M << 4) + j) * N + col;
          if (EPI == 0) {
            ((u16*)Cptr)[idx] = f2bf(acc[M][n][j]);
          } else if (EPI == 2) {
            u16* P = (u16*)Cptr + (size_t)bz * ((size_t)L_SEQ * N);
            P[idx] = f2bf(acc[M][n][j]);
          } else {
            ((u16*)Cptr)[idx] = f2bf(siluf(bf2f(gateB[idx])) * acc[M][n][j]);
          }
        }
      }
    }
  }
}

// ---------------------------------------------------------------------------
// RMSNorm: fp32 in -> bf16 out, D=2048, one block per row
// ---------------------------------------------------------------------------
__global__ __launch_bounds__(256) void rmsnorm_k(
    const float* __restrict__ in, const float* __restrict__ w, u16* __restrict__ out)
{
  const int row = blockIdx.x, tid = threadIdx.x;
  const float* r = in + (size_t)row * DMODEL + tid * 8;
  f32x4 v0 = *(const f32x4*)r;
  f32x4 v1 = *(const f32x4*)(r + 4);
  float ss = v0[0]*v0[0] + v0[1]*v0[1] + v0[2]*v0[2] + v0[3]*v0[3]
           + v1[0]*v1[0] + v1[1]*v1[1] + v1[2]*v1[2] + v1[3]*v1[3];
#pragma unroll
  for (int off = 1; off < 64; off <<= 1) ss += __shfl_xor(ss, off);
  __shared__ float part[4];
  if ((tid & 63) == 0) part[tid >> 6] = ss;
  __syncthreads();
  const float tot = part[0] + part[1] + part[2] + part[3];
  const float scale = rsqrtf(tot * (1.f / DMODEL) + 1e-5f);
  f32x4 w0 = *(const f32x4*)(w + tid * 8);
  f32x4 w1 = *(const f32x4*)(w + tid * 8 + 4);
  u16x8 o;
#pragma unroll
  for (int j = 0; j < 4; ++j) {
    o[j]     = f2bf(v0[j] * scale * w0[j]);
    o[j + 4] = f2bf(v1[j] * scale * w1[j]);
  }
  *(u16x8*)(out + (size_t)row * DMODEL + tid * 8) = o;
}

// ---------------------------------------------------------------------------
// reduce 2 bf16 split-K partials -> bf16 out (in_proj path)
// ---------------------------------------------------------------------------
__global__ __launch_bounds__(256) void red2bf_k(
    const u16* __restrict__ P, u16* __restrict__ out)
{
  const size_t i = ((size_t)blockIdx.x * 256 + threadIdx.x) * 8;
  const size_t stride = (size_t)L_SEQ * DPROJ;
  u16x8 a = *(const u16x8*)(P + i);
  u16x8 b = *(const u16x8*)(P + stride + i);
  u16x8 o;
#pragma unroll
  for (int j = 0; j < 8; ++j) o[j] = f2bf(bf2f(a[j]) + bf2f(b[j]));
  *(u16x8*)(out + i) = o;
}

// ---------------------------------------------------------------------------
// reduce 4 bf16 split-K partials + residual -> hres (fp32), then rmsnorm -> bf16
// ---------------------------------------------------------------------------
__global__ __launch_bounds__(256) void red4_rms_k(
    const u16* __restrict__ P, const float* __restrict__ resid,
    float* __restrict__ hres, const float* __restrict__ w, u16* __restrict__ h2)
{
  const int row = blockIdx.x, tid = threadIdx.x;
  const size_t base = (size_t)row * DMODEL + tid * 8;
  const size_t stride = (size_t)L_SEQ * DMODEL;
  f32x4 v0 = *(const f32x4*)(resid + base);
  f32x4 v1 = *(const f32x4*)(resid + base + 4);
#pragma unroll
  for (int p = 0; p < 4; ++p) {
    u16x8 pv = *(const u16x8*)(P + p * stride + base);
#pragma unroll
    for (int j = 0; j < 4; ++j) { v0[j] += bf2f(pv[j]); v1[j] += bf2f(pv[j + 4]); }
  }
  *(f32x4*)(hres + base) = v0;
  *(f32x4*)(hres + base + 4) = v1;
  float ss = v0[0]*v0[0] + v0[1]*v0[1] + v0[2]*v0[2] + v0[3]*v0[3]
           + v1[0]*v1[0] + v1[1]*v1[1] + v1[2]*v1[2] + v1[3]*v1[3];
#pragma unroll
  for (int off = 1; off < 64; off <<= 1) ss += __shfl_xor(ss, off);
  __shared__ float part[4];
  if ((tid & 63) == 0) part[tid >> 6] = ss;
  __syncthreads();
  const float tot = part[0] + part[1] + part[2] + part[3];
  const float scale = rsqrtf(tot * (1.f / DMODEL) + 1e-5f);
  f32x4 w0 = *(const f32x4*)(w + tid * 8);
  f32x4 w1 = *(const f32x4*)(w + tid * 8 + 4);
  u16x8 o;
#pragma unroll
  for (int j = 0; j < 4; ++j) {
    o[j]     = f2bf(v0[j] * scale * w0[j]);
    o[j + 4] = f2bf(v1[j] * scale * w1[j]);
  }
  *(u16x8*)(h2 + base) = o;
}

// ---------------------------------------------------------------------------
// reduce 4 bf16 split-K partials + residual -> out (fp32)
// ---------------------------------------------------------------------------
__global__ __launch_bounds__(256) void red4_add_k(
    const u16* __restrict__ P, const float* __restrict__ resid, float* __restrict__ out)
{
  const size_t base = ((size_t)blockIdx.x * 256 + threadIdx.x) * 8;
  const size_t stride = (size_t)L_SEQ * DMODEL;
  f32x4 v0 = *(const f32x4*)(resid + base);
  f32x4 v1 = *(const f32x4*)(resid + base + 4);
#pragma unroll
  for (int p = 0; p < 4; ++p) {
    u16x8 pv = *(const u16x8*)(P + p * stride + base);
#pragma unroll
    for (int j = 0; j < 4; ++j) { v0[j] += bf2f(pv[j]); v1[j] += bf2f(pv[j + 4]); }
  }
  *(f32x4*)(out + base) = v0;
  *(f32x4*)(out + base + 4) = v1;
}

// ---------------------------------------------------------------------------
// Gated RMSNorm: y * silu(z) then rmsnorm -> bf16
// ---------------------------------------------------------------------------
__global__ __launch_bounds__(256) void gated_rms_k(
    const float* __restrict__ y, const u16* __restrict__ zx,
    const float* __restrict__ w, u16* __restrict__ out)
{
  const int row = blockIdx.x, tid = threadIdx.x;
  const float* yr = y + (size_t)row * DINNER + tid * 8;
  f32x4 y0 = *(const f32x4*)yr;
  f32x4 y1 = *(const f32x4*)(yr + 4);
  u16x8 zv = *(const u16x8*)(zx + (size_t)row * DPROJ + tid * 8);
  float val[8];
#pragma unroll
  for (int j = 0; j < 4; ++j) {
    val[j]     = y0[j] * siluf(bf2f(zv[j]));
    val[j + 4] = y1[j] * siluf(bf2f(zv[j + 4]));
  }
  float ss = 0.f;
#pragma unroll
  for (int j = 0; j < 8; ++j) ss += val[j] * val[j];
#pragma unroll
  for (int off = 1; off < 64; off <<= 1) ss += __shfl_xor(ss, off);
  __shared__ float part[4];
  if ((tid & 63) == 0) part[tid >> 6] = ss;
  __syncthreads();
  const float tot = part[0] + part[1] + part[2] + part[3];
  const float scale = rsqrtf(tot * (1.f / DINNER) + 1e-5f);
  u16x8 o;
#pragma unroll
  for (int j = 0; j < 8; ++j) o[j] = f2bf(val[j] * scale * w[tid * 8 + j]);
  *(u16x8*)(out + (size_t)row * DINNER + tid * 8) = o;
}

// ---------------------------------------------------------------------------
// Merged: causal depthwise conv (K=4)+SiLU over xBC, and dt/dA precompute.
// ---------------------------------------------------------------------------
__global__ __launch_bounds__(256) void convdt_k(
    const u16* __restrict__ zx, const float* __restrict__ w,
    const float* __restrict__ b, u16* __restrict__ xbc,
    const float* __restrict__ dt_bias, const float* __restrict__ A_log,
    float* __restrict__ dtv, float* __restrict__ dAv)
{
  if (blockIdx.x < 3072) {
    const int flat = blockIdx.x * 256 + threadIdx.x;  // 2048 * 384
    const int t = flat / 384;
    const int c8 = (flat % 384) * 8;
    float acc[8];
    f32x4 b0 = *(const f32x4*)(b + c8);
    f32x4 b1 = *(const f32x4*)(b + c8 + 4);
#pragma unroll
    for (int j = 0; j < 4; ++j) { acc[j] = b0[j]; acc[j + 4] = b1[j]; }
    f32x4 wr[8];
#pragma unroll
    for (int j = 0; j < 8; ++j) wr[j] = *(const f32x4*)(w + (size_t)(c8 + j) * 4);
#pragma unroll
    for (int k = 0; k < 4; ++k) {
      const int tt = t - 3 + k;
      if (tt >= 0) {
        u16x8 xv = *(const u16x8*)(zx + (size_t)tt * DPROJ + DINNER + c8);
#pragma unroll
        for (int j = 0; j < 8; ++j) acc[j] += bf2f(xv[j]) * wr[j][k];
      }
    }
    u16x8 o;
#pragma unroll
    for (int j = 0; j < 8; ++j) o[j] = f2bf(siluf(acc[j]));
    *(u16x8*)(xbc + (size_t)t * CONVCH + c8) = o;
  } else {
    const int flat = (blockIdx.x - 3072) * 256 + threadIdx.x;  // 2048*32
    const int t = flat >> 5, h = flat & 31;
    const float x = bf2f(zx[(size_t)t * DPROJ + (DPROJ - NHEADS) + h]) + dt_bias[h];
    const float sp = (x > 20.f) ? x : log1pf(expf(x));
    const float a = expf(A_log[h]);
    dtv[flat] = sp;
    dAv[flat] = expf(-a * sp);
  }
}

__device__ __forceinline__ void stage16(float* dst, const u16* src) {
  u16x8 a = *(const u16x8*)src;
  u16x8 b = *(const u16x8*)(src + 8);
#pragma unroll
  for (int j = 0; j < 8; ++j) { dst[j] = bf2f(a[j]); dst[8 + j] = bf2f(b[j]); }
}

// ---------------------------------------------------------------------------
// Scan pass A: per (chunk, head) intra-chunk scan with h0=0.
// ---------------------------------------------------------------------------
__global__ __launch_bounds__(256) void scan_a(
    const u16* __restrict__ xbc, const float* __restrict__ dtv,
    const float* __restrict__ dAv, const float* __restrict__ Dvec,
    float* __restrict__ y, float* __restrict__ S,
    float* __restrict__ gam, float* __restrict__ cum)
{
  __shared__ float xs[64][64], Bs[64][64], Cs[64][64];
  __shared__ float dts[64], dAs[64];
  const int c = blockIdx.x, h = blockIdx.y, kv = h >> 2;
  const int tid = threadIdx.x;
  const int t0 = c * CHUNK;
  {
    const int r = tid >> 2, cq = (tid & 3) * 16;
    const u16* base = xbc + (size_t)(t0 + r) * CONVCH;
    stage16(&xs[r][cq], base + kv * 64 + cq);
    stage16(&Bs[r][cq], base + DXB + kv * 64 + cq);
    stage16(&Cs[r][cq], base + 2 * DXB + h * 64 + cq);
    if (tid < 64) {
      dts[tid] = dtv[(size_t)(t0 + tid) * NHEADS + h];
      dAs[tid] = dAv[(size_t)(t0 + tid) * NHEADS + h];
    }
  }
  __syncthreads();
  const int p = tid >> 2, q = tid & 3;
  float hreg[16];
#pragma unroll
  for (int i = 0; i < 16; ++i) hreg[i] = 0.f;
  float cumv = 1.f;
  const float Dh = Dvec[h];
  for (int t = 0; t < CHUNK; ++t) {
    const float dtt = dts[t], dat = dAs[t];
    const float xv = xs[t][p];
    const float u = dtt * xv;
    float a0 = 0.f, a1 = 0.f, a2 = 0.f, a3 = 0.f;
#pragma unroll
    for (int i4 = 0; i4 < 4; ++i4) {
      f32x4 b4 = *(const f32x4*)&Bs[t][q * 16 + i4 * 4];
      f32x4 c4 = *(const f32x4*)&Cs[t][q * 16 + i4 * 4];
#pragma unroll
      for (int j = 0; j < 4; ++j) {
        const int i = i4 * 4 + j;
        hreg[i] = hreg[i] * dat + u * b4[j];
        if (i4 == 0) a0 += hreg[i] * c4[j];
        else if (i4 == 1) a1 += hreg[i] * c4[j];
        else if (i4 == 2) a2 += hreg[i] * c4[j];
        else a3 += hreg[i] * c4[j];
      }
    }
    float accv = (a0 + a1) + (a2 + a3);
    accv += __shfl_xor(accv, 1);
    accv += __shfl_xor(accv, 2);
    cumv *= dat;
    if (q == 0) y[(size_t)(t0 + t) * DINNER + h * 64 + p] = accv + Dh * xv;
    if (tid == 0) cum[(size_t)(t0 + t) * NHEADS + h] = cumv;
  }
  float* Sp = S + ((size_t)(c * NHEADS + h) << 12) + tid * 16;
#pragma unroll
  for (int i4 = 0; i4 < 4; ++i4)
    *(f32x4*)(Sp + i4 * 4) = f32x4{hreg[i4*4], hreg[i4*4+1], hreg[i4*4+2], hreg[i4*4+3]};
  if (tid == 0) gam[c * NHEADS + h] = cumv;
}

// ---------------------------------------------------------------------------
// Scan pass B (parallel): 131072 independent (head, elem) recurrence chains.
// ---------------------------------------------------------------------------
__global__ __launch_bounds__(256) void scan_b(
    const float* __restrict__ S, const float* __restrict__ gam, float* __restrict__ H)
{
  const int g = blockIdx.x * 256 + threadIdx.x;  // 0 .. 32*4096-1
  const int h = g >> 12;
  const int e = g & 4095;
  float hr = 0.f;
  for (int c = 0; c < NCHUNK; ++c) {
    const size_t base = (((size_t)(c * NHEADS + h)) << 12) + e;
    H[base] = hr;
    hr = gam[c * NHEADS + h] * hr + S[base];
  }
}

// ---------------------------------------------------------------------------
// Scan pass C: y += cumdA_t * (C_t . H[chunk])
// ---------------------------------------------------------------------------
__global__ __launch_bounds__(256) void scan_c(
    const u16* __restrict__ xbc, const float* __restrict__ cum,
    const float* __restrict__ H, float* __restrict__ y)
{
  __shared__ float Cs[64][64];
  __shared__ float cums[64];
  const int c = blockIdx.x, h = blockIdx.y, tid = threadIdx.x;
  const int t0 = c * CHUNK;
  {
    const int r = tid >> 2, cq = (tid & 3) * 16;
    stage16(&Cs[r][cq], xbc + (size_t)(t0 + r) * CONVCH + 2 * DXB + h * 64 + cq);
    if (tid < 64) cums[tid] = cum[(size_t)(t0 + tid) * NHEADS + h];
  }
  const int p = tid >> 2, q = tid & 3;
  float hr[16];
  const size_t base = ((size_t)(c * NHEADS + h) << 12) + tid * 16;
#pragma unroll
  for (int i4 = 0; i4 < 4; ++i4) {
    f32x4 v = *(const f32x4*)(H + base + i4 * 4);
#pragma unroll
    for (int j = 0; j < 4; ++j) hr[i4 * 4 + j] = v[j];
  }
  __syncthreads();
  for (int t = 0; t < CHUNK; ++t) {
    float accv = 0.f;
#pragma unroll
    for (int i4 = 0; i4 < 4; ++i4) {
      f32x4 c4 = *(const f32x4*)&Cs[t][q * 16 + i4 * 4];
#pragma unroll
      for (int j = 0; j < 4; ++j) accv += hr[i4 * 4 + j] * c4[j];
    }
    accv += __shfl_xor(accv, 1);
    accv += __shfl_xor(accv, 2);
    if (q == 0) {
      const size_t idx = (size_t)(t0 + t) * DINNER + h * 64 + p;
      y[idx] += cums[t] * accv;
    }
  }
}

// ---------------------------------------------------------------------------
extern "C" void kernel_launch(void* const* d_in, const int* in_sizes, int n_in,
                              void* d_out, int out_size, void* d_ws, size_t ws_size,
                              hipStream_t stream) {
  const float* hs         = (const float*)d_in[0];
  const float* in_proj_w  = (const float*)d_in[1];
  const float* conv_w     = (const float*)d_in[2];
  const float* conv_b     = (const float*)d_in[3];
  const float* dt_bias    = (const float*)d_in[4];
  const float* A_log      = (const float*)d_in[5];
  const float* Dv         = (const float*)d_in[6];
  const float* ssm_w      = (const float*)d_in[7];
  const float* out_proj_w = (const float*)d_in[8];
  const float* in_ln_w    = (const float*)d_in[9];
  const float* post_ln_w  = (const float*)d_in[10];
  const float* gate_w     = (const float*)d_in[11];
  const float* up_w       = (const float*)d_in[12];
  const float* down_w     = (const float*)d_in[13];
  float* out = (float*)d_out;

  char* ws = (char*)d_ws;
  size_t off = 0;
  auto alloc = [&](size_t bytes) -> void* {
    void* p = ws + off;
    off = (off + bytes + 255) & ~(size_t)255;
    return p;
  };
  // persistent bf16 weights (in_proj padded to 5376 rows)
  u16* wip = (u16*)alloc((size_t)DPROJ_PAD * DMODEL * 2);
  u16* wop = (u16*)alloc((size_t)DMODEL * DINNER * 2);
  u16* wg  = (u16*)alloc((size_t)DFF    * DMODEL * 2);
  u16* wu  = (u16*)alloc((size_t)DFF    * DMODEL * 2);
  u16* wd  = (u16*)alloc((size_t)DMODEL * DFF    * 2);
  // dynamic region. Overlays (all bf16 partials now):
  //   pIn (2x L*DPROJ u16 = 42.2MB) overlays xbc+Sv+Hv (live only before conv)
  //   pK  (4x L*DMODEL u16 = 33.5MB) overlays zx+xbc (live after gated_rms)
  u16*   zx  = (u16*)  alloc((size_t)L_SEQ * DPROJ * 2);
  u16*   xbc = (u16*)  alloc((size_t)L_SEQ * CONVCH * 2);
  float* Sv  = (float*)alloc((size_t)NCHUNK * NHEADS * 4096 * 4);
  float* Hv  = (float*)alloc((size_t)NCHUNK * NHEADS * 4096 * 4);
  u16*   pIn = xbc;
  u16*   pK  = zx;
  float* dtv = (float*)alloc((size_t)L_SEQ * NHEADS * 4);
  float* dAv = (float*)alloc((size_t)L_SEQ * NHEADS * 4);
  float* cum = (float*)alloc((size_t)L_SEQ * NHEADS * 4);
  float* gam = (float*)alloc((size_t)NCHUNK * NHEADS * 4);
  float* yv  = (float*)alloc((size_t)L_SEQ * DINNER * 4);
  float* hres= (float*)alloc((size_t)L_SEQ * DMODEL * 4);
  u16*  gateb= (u16*)  alloc((size_t)L_SEQ * DFF * 2);
  u16*  hslot= (u16*)  alloc((size_t)L_SEQ * DMODEL * 2);
  (void)ws_size; (void)in_sizes; (void)n_in; (void)out_size;

  // 0. weight fp32 -> bf16
  cvt_pad_k<<<(DPROJ_PAD * DMODEL / 8) / 256, 256, 0, stream>>>(in_proj_w, wip);
  cvt_k<<<DMODEL * DINNER / 8 / 256, 256, 0, stream>>>(out_proj_w, wop, DMODEL * DINNER / 8);
  cvt_k<<<DFF * DMODEL / 8 / 256, 256, 0, stream>>>(gate_w, wg, DFF * DMODEL / 8);
  cvt_k<<<DFF * DMODEL / 8 / 256, 256, 0, stream>>>(up_w, wu, DFF * DMODEL / 8);
  cvt_k<<<DMODEL * DFF / 8 / 256, 256, 0, stream>>>(down_w, wd, DMODEL * DFF / 8);

  // 1. input rmsnorm -> bf16
  rmsnorm_k<<<L_SEQ, 256, 0, stream>>>(hs, in_ln_w, hslot);
  // 2. in_proj GEMM split-K=2 (336 blocks = 1.3/CU vs 168 = 0.65/CU before)
  //    -> bf16 partials in pIn (xbc..Hv region, dead until conv), then reduce -> zx
  gemm8<2, 2><<<21 * 8 * 2, 512, 0, stream>>>(hslot, wip, pIn, nullptr, DPROJ, DMODEL, 21);
  red2bf_k<<<(L_SEQ * DPROJ / 8) / 256, 256, 0, stream>>>(pIn, zx);
  // 3. conv + silu + dt/dA (merged; overwrites pIn region, now dead)
  convdt_k<<<3072 + 256, 256, 0, stream>>>(zx, conv_w, conv_b, xbc, dt_bias, A_log, dtv, dAv);
  // 4-6. chunked selective scan
  scan_a<<<dim3(NCHUNK, NHEADS), 256, 0, stream>>>(xbc, dtv, dAv, Dv, yv, Sv, gam, cum);
  scan_b<<<512, 256, 0, stream>>>(Sv, gam, Hv);
  scan_c<<<dim3(NCHUNK, NHEADS), 256, 0, stream>>>(xbc, cum, Hv, yv);
  // 7. gated rmsnorm -> bf16
  gated_rms_k<<<L_SEQ, 256, 0, stream>>>(yv, zx, ssm_w, hslot);
  // 8. out_proj GEMM split-K=4 -> bf16 partials (overlay zx+xbc, now dead)
  gemm8<2, 4><<<8 * 8 * 4, 512, 0, stream>>>(hslot, wop, pK, nullptr, DMODEL, DINNER, 8);
  // 9. reduce + hs residual -> hres ; post rmsnorm -> bf16
  red4_rms_k<<<L_SEQ, 256, 0, stream>>>(pK, hs, hres, post_ln_w, hslot);
  // 10. gate GEMM
  gemm8<0, 1><<<32 * 8, 512, 0, stream>>>(hslot, wg, gateb, nullptr, DFF, DMODEL, 32);
  // 11. up GEMM with fused act
  gemm8<3, 1><<<32 * 8, 512, 0, stream>>>(hslot, wu, gateb, gateb, DFF, DMODEL, 32);
  // 12. down GEMM split-K=4 -> bf16 partials
  gemm8<2, 4><<<8 * 8 * 4, 512, 0, stream>>>(gateb, wd, pK, nullptr, DMODEL, DFF, 8);
  // 13. reduce + hres residual -> out
  red4_add_k<<<(L_SEQ * DMODEL / 8) / 256, 256, 0, stream>>>(pK, hres, out);
}

// Round 15
// 500.826 us; speedup vs baseline: 1.0210x; 1.0210x over previous
//
#include <hip/hip_runtime.h>

typedef unsigned short u16;
typedef unsigned int u32;
typedef float f32x4 __attribute__((ext_vector_type(4)));
typedef __bf16 bf16x8 __attribute__((ext_vector_type(8)));
typedef unsigned short u16x8 __attribute__((ext_vector_type(8)));

#define L_SEQ 2048
#define DMODEL 2048
#define DINNER 2048
#define DXB 512
#define NHEADS 32
#define DPROJ 5152   // 2*DINNER + 2*DXB + NHEADS
#define DPROJ_PAD 5376  // 21 * 256
#define CONVCH 3072  // 2*DXB + DINNER
#define DFF 8192
#define NCHUNK 32
#define CHUNK 64

__device__ __forceinline__ float bf2f(u16 u) {
  union { unsigned int i; float f; } v; v.i = ((unsigned int)u) << 16; return v.f;
}
__device__ __forceinline__ u16 f2bf(float f) {
  union { float f; unsigned int i; } v; v.f = f;
  unsigned int u = v.i;
  u += 0x7FFFu + ((u >> 16) & 1u);
  return (u16)(u >> 16);
}
__device__ __forceinline__ float siluf(float x) { return x / (1.f + __expf(-x)); }

#define GL16(gsrc, ldst) \
  __builtin_amdgcn_global_load_lds((const __attribute__((address_space(1))) u32*)(gsrc), \
                                   (__attribute__((address_space(3))) u32*)(ldst), 16, 0, 0)
#define SBAR() __builtin_amdgcn_s_barrier()
#define WAIT_VM4() asm volatile("s_waitcnt vmcnt(4)" ::: "memory")
#define WAIT_VM0() asm volatile("s_waitcnt vmcnt(0)" ::: "memory")

// ---------------------------------------------------------------------------
// fp32 -> bf16 weight conversion (standalone; fused-in-GEMM REJECTED round 10)
// ---------------------------------------------------------------------------
__global__ __launch_bounds__(256) void cvt_k(
    const float* __restrict__ s, u16* __restrict__ d, int n8)
{
  const int i = blockIdx.x * 256 + threadIdx.x;
  if (i >= n8) return;
  f32x4 a = *(const f32x4*)(s + (size_t)i * 8);
  f32x4 b = *(const f32x4*)(s + (size_t)i * 8 + 4);
  u16x8 o;
#pragma unroll
  for (int j = 0; j < 4; ++j) { o[j] = f2bf(a[j]); o[j + 4] = f2bf(b[j]); }
  *(u16x8*)(d + (size_t)i * 8) = o;
}

// in_proj variant: pad rows [DPROJ, DPROJ_PAD) with zeros
__global__ __launch_bounds__(256) void cvt_pad_k(
    const float* __restrict__ s, u16* __restrict__ d)
{
  const int i = blockIdx.x * 256 + threadIdx.x;  // over DPROJ_PAD*2048/8
  const int row = (i * 8) >> 11;
  u16x8 o;
  if (row < DPROJ) {
    f32x4 a = *(const f32x4*)(s + (size_t)i * 8);
    f32x4 b = *(const f32x4*)(s + (size_t)i * 8 + 4);
#pragma unroll
    for (int j = 0; j < 4; ++j) { o[j] = f2bf(a[j]); o[j + 4] = f2bf(b[j]); }
  } else {
#pragma unroll
    for (int j = 0; j < 8; ++j) o[j] = 0;
  }
  *(u16x8*)(d + (size_t)i * 8) = o;
}

// ---------------------------------------------------------------------------
// 256x256 8-phase GEMM (round-7/11 config — validated local optimum ~860 TF):
// 8 FINE phases (phase granularity creates wave role-diversity the CU
// scheduler exploits; 4-merged-phase variant regressed 28%, round 12).
// Compiler-scheduled lgkm, ONE barrier per phase (post-MFMA), counted
// vmcnt(4) at ph4/ph8 (T4), setprio (T5), pre-swizzled gload + XOR ds_read
// (T2), XCD-bijective chunk + column-major decode (T1).
// EPI 0: bf16. EPI 2: fp32 split-K partial. EPI 3: silu(gateB)*acc -> bf16.
// [round-14 bf16-partials + in_proj split-K=2 REJECTED: +10us net — extra
//  reduce traffic and halved K/block pipeline amortization]
// ---------------------------------------------------------------------------
template<int MH, int NH>
__device__ __forceinline__ void mfma16(f32x4 (&acc)[8][4], const bf16x8 (&af)[4][2],
                                       const bf16x8 (&bfq)[2][2][2]) {
#pragma unroll
  for (int s = 0; s < 2; ++s)
#pragma unroll
    for (int m = 0; m < 4; ++m)
#pragma unroll
      for (int n = 0; n < 2; ++n)
        acc[MH * 4 + m][NH * 2 + n] = __builtin_amdgcn_mfma_f32_16x16x32_bf16(
            af[m][s], bfq[NH][n][s], acc[MH * 4 + m][NH * 2 + n], 0, 0, 0);
}

template<int EPI, int SPLIT>
__global__ __launch_bounds__(512, 2) void gemm8(
    const u16* __restrict__ A, const u16* __restrict__ W,
    void* __restrict__ Cptr, const u16* __restrict__ gateB,
    const int N, const int K, const int gx)
{
  __shared__ u16 sm[65536];  // 128 KiB: [buf<<15] + [A:0 | B:16384] + row*64
  const int tid = threadIdx.x;
  const int wid = tid >> 6, ln = tid & 63;
  const int wm = wid >> 2, wn = wid & 3;

  const int nwg = gridDim.x;
  int wg = (int)blockIdx.x;
  wg = (wg & 7) * (nwg >> 3) + (wg >> 3);
  const int tilesPerZ = gx << 3;
  const int bz = wg / tilesPerZ;
  const int rem = wg - bz * tilesPerZ;
  const int bx = rem >> 3;
  const int by = rem & 7;
  const int m0 = by << 8, n0 = bx << 8;
  const int NT = (K >> 6) / SPLIT;
  const int ktB = bz * NT;

  f32x4 acc[8][4];
#pragma unroll
  for (int i = 0; i < 8; ++i)
#pragma unroll
    for (int j = 0; j < 4; ++j) acc[i][j] = f32x4{0.f, 0.f, 0.f, 0.f};

  const int l8r = ln >> 3;                 // 0..7
  const int schunk = (ln & 7) ^ l8r;       // pre-swizzled source chunk
  const int lr16 = ln & 15;
  const int q4 = ln >> 4;
  const int swz = ln & 7;
  const int c0 = ((q4 ^ swz) << 3);        // u16 offset of k-slice 0 chunk

  auto stageA = [&](int buf, int kt, int h) {
#pragma unroll
    for (int g = 0; g < 2; ++g) {
      const int rr = (wid << 3) + l8r;
      const size_t grow = (size_t)(m0 + (g << 7) + (h << 6) + rr);
      const u16* src = A + grow * K + (size_t)((ktB + kt) << 6) + (schunk << 3);
      u16* dst = &sm[(buf << 15) + (((h << 7) + (g << 6) + (wid << 3)) << 6)];
      GL16(src, dst);
    }
  };
  auto stageB = [&](int buf, int kt, int h) {
#pragma unroll
    for (int g = 0; g < 2; ++g) {
      const int v = (g << 6) + (wid << 3) + l8r;
      const int grow = n0 + ((v >> 5) << 6) + (h << 5) + (v & 31);
      const u16* src = W + (size_t)grow * K + (size_t)((ktB + kt) << 6) + (schunk << 3);
      u16* dst = &sm[(buf << 15) + 16384 + (((h << 7) + (g << 6) + (wid << 3)) << 6)];
      GL16(src, dst);
    }
  };

  bf16x8 af[4][2], bfq[2][2][2];
  auto loadA = [&](int buf, int mh) {
#pragma unroll
    for (int m = 0; m < 4; ++m) {
      const int lrA = (mh << 7) + (wm << 6) + (m << 4) + lr16;
      const u16* p = &sm[(buf << 15) + (lrA << 6)];
      af[m][0] = *(const bf16x8*)(p + c0);
      af[m][1] = *(const bf16x8*)(p + (c0 ^ 32));
    }
  };
  auto loadB = [&](int buf, int nh) {
#pragma unroll
    for (int n = 0; n < 2; ++n) {
      const int lrB = (nh << 7) + (wn << 5) + (n << 4) + lr16;
      const u16* p = &sm[(buf << 15) + 16384 + (lrB << 6)];
      bfq[nh][n][0] = *(const bf16x8*)(p + c0);
      bfq[nh][n][1] = *(const bf16x8*)(p + (c0 ^ 32));
    }
  };

  // Prologue: kt0 full (8 loads) + kt1 {A-h0, B-h1} (4 loads); wait kt0.
  stageA(0, 0, 0); stageA(0, 0, 1); stageB(0, 0, 0); stageB(0, 0, 1);
  stageA(1, 1, 0); stageB(1, 1, 1);
  WAIT_VM4();
  SBAR();

  for (int kt = 0; kt < NT; kt += 2) {
    const bool s2 = (kt + 2) < NT, s3 = (kt + 3) < NT;
    // ph1: buf0 quad(0,0)
    loadA(0, 0); loadB(0, 0);
    stageA(1, kt + 1, 1);
    __builtin_amdgcn_s_setprio(1); mfma16<0, 0>(acc, af, bfq); __builtin_amdgcn_s_setprio(0);
    SBAR();
    // ph2: quad(0,1)
    loadB(0, 1);
    stageB(1, kt + 1, 0);
    __builtin_amdgcn_s_setprio(1); mfma16<0, 1>(acc, af, bfq); __builtin_amdgcn_s_setprio(0);
    SBAR();
    // ph3: quad(1,1)
    loadA(0, 1);
    if (s2) stageA(0, kt + 2, 0);
    __builtin_amdgcn_s_setprio(1); mfma16<1, 1>(acc, af, bfq); __builtin_amdgcn_s_setprio(0);
    SBAR();
    // ph4: quad(1,0) pure-MFMA; counted vmcnt before switching to buf1
    if (s2) stageB(0, kt + 2, 1);
    __builtin_amdgcn_s_setprio(1); mfma16<1, 0>(acc, af, bfq); __builtin_amdgcn_s_setprio(0);
    if (s2) { WAIT_VM4(); } else { WAIT_VM0(); }
    SBAR();
    // ph5: buf1 quad(0,0)
    loadA(1, 0); loadB(1, 0);
    if (s2) stageA(0, kt + 2, 1);
    __builtin_amdgcn_s_setprio(1); mfma16<0, 0>(acc, af, bfq); __builtin_amdgcn_s_setprio(0);
    SBAR();
    // ph6: quad(0,1)
    loadB(1, 1);
    if (s2) stageB(0, kt + 2, 0);
    __builtin_amdgcn_s_setprio(1); mfma16<0, 1>(acc, af, bfq); __builtin_amdgcn_s_setprio(0);
    SBAR();
    // ph7: quad(1,1)
    loadA(1, 1);
    if (s3) stageA(1, kt + 3, 0);
    __builtin_amdgcn_s_setprio(1); mfma16<1, 1>(acc, af, bfq); __builtin_amdgcn_s_setprio(0);
    SBAR();
    // ph8: quad(1,0) pure-MFMA; counted vmcnt before next iter reads buf0
    if (s3) stageB(1, kt + 3, 1);
    __builtin_amdgcn_s_setprio(1); mfma16<1, 0>(acc, af, bfq); __builtin_amdgcn_s_setprio(0);
    if (s2) { if (s3) { WAIT_VM4(); } else { WAIT_VM0(); } }
    SBAR();
  }

  // Epilogue: C/D layout col=ln&15, row=(ln>>4)*4+j (m89)
  const int crow0 = m0 + (wm << 7) + (q4 << 2);
  const int ccol0 = n0 + (wn << 6) + lr16;
#pragma unroll
  for (int M = 0; M < 8; ++M) {
#pragma unroll
    for (int n = 0; n < 4; ++n) {
      const int col = ccol0 + (n << 4);
      if (col < N) {
#pragma unroll
        for (int j = 0; j < 4; ++j) {
          const size_t idx = (size_t)(crow0 + (M << 4) + j) * N + col;
          if (EPI == 0) {
            ((u16*)Cptr)[idx] = f2bf(acc[M][n][j]);
          } else if (EPI == 2) {
            float* P = (float*)Cptr + (size_t)bz * ((size_t)L_SEQ * N);
            P[idx] = acc[M][n][j];
          } else {
            ((u16*)Cptr)[idx] = f2bf(siluf(bf2f(gateB[idx])) * acc[M][n][j]);
          }
        }
      }
    }
  }
}

// ---------------------------------------------------------------------------
// RMSNorm: fp32 in -> bf16 out, D=2048, one block per row
// ---------------------------------------------------------------------------
__global__ __launch_bounds__(256) void rmsnorm_k(
    const float* __restrict__ in, const float* __restrict__ w, u16* __restrict__ out)
{
  const int row = blockIdx.x, tid = threadIdx.x;
  const float* r = in + (size_t)row * DMODEL + tid * 8;
  f32x4 v0 = *(const f32x4*)r;
  f32x4 v1 = *(const f32x4*)(r + 4);
  float ss = v0[0]*v0[0] + v0[1]*v0[1] + v0[2]*v0[2] + v0[3]*v0[3]
           + v1[0]*v1[0] + v1[1]*v1[1] + v1[2]*v1[2] + v1[3]*v1[3];
#pragma unroll
  for (int off = 1; off < 64; off <<= 1) ss += __shfl_xor(ss, off);
  __shared__ float part[4];
  if ((tid & 63) == 0) part[tid >> 6] = ss;
  __syncthreads();
  const float tot = part[0] + part[1] + part[2] + part[3];
  const float scale = rsqrtf(tot * (1.f / DMODEL) + 1e-5f);
  f32x4 w0 = *(const f32x4*)(w + tid * 8);
  f32x4 w1 = *(const f32x4*)(w + tid * 8 + 4);
  u16x8 o;
#pragma unroll
  for (int j = 0; j < 4; ++j) {
    o[j]     = f2bf(v0[j] * scale * w0[j]);
    o[j + 4] = f2bf(v1[j] * scale * w1[j]);
  }
  *(u16x8*)(out + (size_t)row * DMODEL + tid * 8) = o;
}

// ---------------------------------------------------------------------------
// reduce 4 split-K partials + residual -> hres (fp32), then rmsnorm -> h2 bf16
// ---------------------------------------------------------------------------
__global__ __launch_bounds__(256) void red4_rms_k(
    const float* __restrict__ P, const float* __restrict__ resid,
    float* __restrict__ hres, const float* __restrict__ w, u16* __restrict__ h2)
{
  const int row = blockIdx.x, tid = threadIdx.x;
  const size_t base = (size_t)row * DMODEL + tid * 8;
  const size_t stride = (size_t)L_SEQ * DMODEL;
  f32x4 v0 = *(const f32x4*)(resid + base);
  f32x4 v1 = *(const f32x4*)(resid + base + 4);
#pragma unroll
  for (int p = 0; p < 4; ++p) {
    v0 += *(const f32x4*)(P + p * stride + base);
    v1 += *(const f32x4*)(P + p * stride + base + 4);
  }
  *(f32x4*)(hres + base) = v0;
  *(f32x4*)(hres + base + 4) = v1;
  float ss = v0[0]*v0[0] + v0[1]*v0[1] + v0[2]*v0[2] + v0[3]*v0[3]
           + v1[0]*v1[0] + v1[1]*v1[1] + v1[2]*v1[2] + v1[3]*v1[3];
#pragma unroll
  for (int off = 1; off < 64; off <<= 1) ss += __shfl_xor(ss, off);
  __shared__ float part[4];
  if ((tid & 63) == 0) part[tid >> 6] = ss;
  __syncthreads();
  const float tot = part[0] + part[1] + part[2] + part[3];
  const float scale = rsqrtf(tot * (1.f / DMODEL) + 1e-5f);
  f32x4 w0 = *(const f32x4*)(w + tid * 8);
  f32x4 w1 = *(const f32x4*)(w + tid * 8 + 4);
  u16x8 o;
#pragma unroll
  for (int j = 0; j < 4; ++j) {
    o[j]     = f2bf(v0[j] * scale * w0[j]);
    o[j + 4] = f2bf(v1[j] * scale * w1[j]);
  }
  *(u16x8*)(h2 + base) = o;
}

// ---------------------------------------------------------------------------
// reduce 4 split-K partials + residual -> out (fp32)
// ---------------------------------------------------------------------------
__global__ __launch_bounds__(256) void red4_add_k(
    const float* __restrict__ P, const float* __restrict__ resid, float* __restrict__ out)
{
  const size_t base = ((size_t)blockIdx.x * 256 + threadIdx.x) * 8;
  const size_t stride = (size_t)L_SEQ * DMODEL;
  f32x4 v0 = *(const f32x4*)(resid + base);
  f32x4 v1 = *(const f32x4*)(resid + base + 4);
#pragma unroll
  for (int p = 0; p < 4; ++p) {
    v0 += *(const f32x4*)(P + p * stride + base);
    v1 += *(const f32x4*)(P + p * stride + base + 4);
  }
  *(f32x4*)(out + base) = v0;
  *(f32x4*)(out + base + 4) = v1;
}

// ---------------------------------------------------------------------------
// Gated RMSNorm: y * silu(z) then rmsnorm -> bf16
// ---------------------------------------------------------------------------
__global__ __launch_bounds__(256) void gated_rms_k(
    const float* __restrict__ y, const u16* __restrict__ zx,
    const float* __restrict__ w, u16* __restrict__ out)
{
  const int row = blockIdx.x, tid = threadIdx.x;
  const float* yr = y + (size_t)row * DINNER + tid * 8;
  f32x4 y0 = *(const f32x4*)yr;
  f32x4 y1 = *(const f32x4*)(yr + 4);
  u16x8 zv = *(const u16x8*)(zx + (size_t)row * DPROJ + tid * 8);
  float val[8];
#pragma unroll
  for (int j = 0; j < 4; ++j) {
    val[j]     = y0[j] * siluf(bf2f(zv[j]));
    val[j + 4] = y1[j] * siluf(bf2f(zv[j + 4]));
  }
  float ss = 0.f;
#pragma unroll
  for (int j = 0; j < 8; ++j) ss += val[j] * val[j];
#pragma unroll
  for (int off = 1; off < 64; off <<= 1) ss += __shfl_xor(ss, off);
  __shared__ float part[4];
  if ((tid & 63) == 0) part[tid >> 6] = ss;
  __syncthreads();
  const float tot = part[0] + part[1] + part[2] + part[3];
  const float scale = rsqrtf(tot * (1.f / DINNER) + 1e-5f);
  u16x8 o;
#pragma unroll
  for (int j = 0; j < 8; ++j) o[j] = f2bf(val[j] * scale * w[tid * 8 + j]);
  *(u16x8*)(out + (size_t)row * DINNER + tid * 8) = o;
}

// ---------------------------------------------------------------------------
// Merged: causal depthwise conv (K=4)+SiLU over xBC, and dt/dA precompute.
// Blocks [0, 3072) do conv; blocks [3072, 3328) do dt.
// ---------------------------------------------------------------------------
__global__ __launch_bounds__(256) void convdt_k(
    const u16* __restrict__ zx, const float* __restrict__ w,
    const float* __restrict__ b, u16* __restrict__ xbc,
    const float* __restrict__ dt_bias, const float* __restrict__ A_log,
    float* __restrict__ dtv, float* __restrict__ dAv)
{
  if (blockIdx.x < 3072) {
    const int flat = blockIdx.x * 256 + threadIdx.x;  // 2048 * 384
    const int t = flat / 384;
    const int c8 = (flat % 384) * 8;
    float acc[8];
    f32x4 b0 = *(const f32x4*)(b + c8);
    f32x4 b1 = *(const f32x4*)(b + c8 + 4);
#pragma unroll
    for (int j = 0; j < 4; ++j) { acc[j] = b0[j]; acc[j + 4] = b1[j]; }
    f32x4 wr[8];
#pragma unroll
    for (int j = 0; j < 8; ++j) wr[j] = *(const f32x4*)(w + (size_t)(c8 + j) * 4);
#pragma unroll
    for (int k = 0; k < 4; ++k) {
      const int tt = t - 3 + k;
      if (tt >= 0) {
        u16x8 xv = *(const u16x8*)(zx + (size_t)tt * DPROJ + DINNER + c8);
#pragma unroll
        for (int j = 0; j < 8; ++j) acc[j] += bf2f(xv[j]) * wr[j][k];
      }
    }
    u16x8 o;
#pragma unroll
    for (int j = 0; j < 8; ++j) o[j] = f2bf(siluf(acc[j]));
    *(u16x8*)(xbc + (size_t)t * CONVCH + c8) = o;
  } else {
    const int flat = (blockIdx.x - 3072) * 256 + threadIdx.x;  // 2048*32
    const int t = flat >> 5, h = flat & 31;
    const float x = bf2f(zx[(size_t)t * DPROJ + (DPROJ - NHEADS) + h]) + dt_bias[h];
    const float sp = (x > 20.f) ? x : log1pf(expf(x));
    const float a = expf(A_log[h]);
    dtv[flat] = sp;
    dAv[flat] = expf(-a * sp);
  }
}

__device__ __forceinline__ void stage16(float* dst, const u16* src) {
  u16x8 a = *(const u16x8*)src;
  u16x8 b = *(const u16x8*)(src + 8);
#pragma unroll
  for (int j = 0; j < 8; ++j) { dst[j] = bf2f(a[j]); dst[8 + j] = bf2f(b[j]); }
}

// ---------------------------------------------------------------------------
// Scan pass A: per (chunk, head) intra-chunk scan with h0=0.
// ---------------------------------------------------------------------------
__global__ __launch_bounds__(256) void scan_a(
    const u16* __restrict__ xbc, const float* __restrict__ dtv,
    const float* __restrict__ dAv, const float* __restrict__ Dvec,
    float* __restrict__ y, float* __restrict__ S,
    float* __restrict__ gam, float* __restrict__ cum)
{
  __shared__ float xs[64][64], Bs[64][64], Cs[64][64];
  __shared__ float dts[64], dAs[64];
  const int c = blockIdx.x, h = blockIdx.y, kv = h >> 2;
  const int tid = threadIdx.x;
  const int t0 = c * CHUNK;
  {
    const int r = tid >> 2, cq = (tid & 3) * 16;
    const u16* base = xbc + (size_t)(t0 + r) * CONVCH;
    stage16(&xs[r][cq], base + kv * 64 + cq);
    stage16(&Bs[r][cq], base + DXB + kv * 64 + cq);
    stage16(&Cs[r][cq], base + 2 * DXB + h * 64 + cq);
    if (tid < 64) {
      dts[tid] = dtv[(size_t)(t0 + tid) * NHEADS + h];
      dAs[tid] = dAv[(size_t)(t0 + tid) * NHEADS + h];
    }
  }
  __syncthreads();
  const int p = tid >> 2, q = tid & 3;
  float hreg[16];
#pragma unroll
  for (int i = 0; i < 16; ++i) hreg[i] = 0.f;
  float cumv = 1.f;
  const float Dh = Dvec[h];
  for (int t = 0; t < CHUNK; ++t) {
    const float dtt = dts[t], dat = dAs[t];
    const float xv = xs[t][p];
    const float u = dtt * xv;
    float a0 = 0.f, a1 = 0.f, a2 = 0.f, a3 = 0.f;
#pragma unroll
    for (int i4 = 0; i4 < 4; ++i4) {
      f32x4 b4 = *(const f32x4*)&Bs[t][q * 16 + i4 * 4];
      f32x4 c4 = *(const f32x4*)&Cs[t][q * 16 + i4 * 4];
#pragma unroll
      for (int j = 0; j < 4; ++j) {
        const int i = i4 * 4 + j;
        hreg[i] = hreg[i] * dat + u * b4[j];
        if (i4 == 0) a0 += hreg[i] * c4[j];
        else if (i4 == 1) a1 += hreg[i] * c4[j];
        else if (i4 == 2) a2 += hreg[i] * c4[j];
        else a3 += hreg[i] * c4[j];
      }
    }
    float accv = (a0 + a1) + (a2 + a3);
    accv += __shfl_xor(accv, 1);
    accv += __shfl_xor(accv, 2);
    cumv *= dat;
    if (q == 0) y[(size_t)(t0 + t) * DINNER + h * 64 + p] = accv + Dh * xv;
    if (tid == 0) cum[(size_t)(t0 + t) * NHEADS + h] = cumv;
  }
  float* Sp = S + ((size_t)(c * NHEADS + h) << 12) + tid * 16;
#pragma unroll
  for (int i4 = 0; i4 < 4; ++i4)
    *(f32x4*)(Sp + i4 * 4) = f32x4{hreg[i4*4], hreg[i4*4+1], hreg[i4*4+2], hreg[i4*4+3]};
  if (tid == 0) gam[c * NHEADS + h] = cumv;
}

// ---------------------------------------------------------------------------
// Scan pass B (parallel): 131072 independent (head, elem) recurrence chains.
// ---------------------------------------------------------------------------
__global__ __launch_bounds__(256) void scan_b(
    const float* __restrict__ S, const float* __restrict__ gam, float* __restrict__ H)
{
  const int g = blockIdx.x * 256 + threadIdx.x;  // 0 .. 32*4096-1
  const int h = g >> 12;
  const int e = g & 4095;
  float hr = 0.f;
  for (int c = 0; c < NCHUNK; ++c) {
    const size_t base = (((size_t)(c * NHEADS + h)) << 12) + e;
    H[base] = hr;
    hr = gam[c * NHEADS + h] * hr + S[base];
  }
}

// ---------------------------------------------------------------------------
// Scan pass C: y += cumdA_t * (C_t . H[chunk])
// ---------------------------------------------------------------------------
__global__ __launch_bounds__(256) void scan_c(
    const u16* __restrict__ xbc, const float* __restrict__ cum,
    const float* __restrict__ H, float* __restrict__ y)
{
  __shared__ float Cs[64][64];
  __shared__ float cums[64];
  const int c = blockIdx.x, h = blockIdx.y, tid = threadIdx.x;
  const int t0 = c * CHUNK;
  {
    const int r = tid >> 2, cq = (tid & 3) * 16;
    stage16(&Cs[r][cq], xbc + (size_t)(t0 + r) * CONVCH + 2 * DXB + h * 64 + cq);
    if (tid < 64) cums[tid] = cum[(size_t)(t0 + tid) * NHEADS + h];
  }
  const int p = tid >> 2, q = tid & 3;
  float hr[16];
  const size_t base = ((size_t)(c * NHEADS + h) << 12) + tid * 16;
#pragma unroll
  for (int i4 = 0; i4 < 4; ++i4) {
    f32x4 v = *(const f32x4*)(H + base + i4 * 4);
#pragma unroll
    for (int j = 0; j < 4; ++j) hr[i4 * 4 + j] = v[j];
  }
  __syncthreads();
  for (int t = 0; t < CHUNK; ++t) {
    float accv = 0.f;
#pragma unroll
    for (int i4 = 0; i4 < 4; ++i4) {
      f32x4 c4 = *(const f32x4*)&Cs[t][q * 16 + i4 * 4];
#pragma unroll
      for (int j = 0; j < 4; ++j) accv += hr[i4 * 4 + j] * c4[j];
    }
    accv += __shfl_xor(accv, 1);
    accv += __shfl_xor(accv, 2);
    if (q == 0) {
      const size_t idx = (size_t)(t0 + t) * DINNER + h * 64 + p;
      y[idx] += cums[t] * accv;
    }
  }
}

// ---------------------------------------------------------------------------
extern "C" void kernel_launch(void* const* d_in, const int* in_sizes, int n_in,
                              void* d_out, int out_size, void* d_ws, size_t ws_size,
                              hipStream_t stream) {
  const float* hs         = (const float*)d_in[0];
  const float* in_proj_w  = (const float*)d_in[1];
  const float* conv_w     = (const float*)d_in[2];
  const float* conv_b     = (const float*)d_in[3];
  const float* dt_bias    = (const float*)d_in[4];
  const float* A_log      = (const float*)d_in[5];
  const float* Dv         = (const float*)d_in[6];
  const float* ssm_w      = (const float*)d_in[7];
  const float* out_proj_w = (const float*)d_in[8];
  const float* in_ln_w    = (const float*)d_in[9];
  const float* post_ln_w  = (const float*)d_in[10];
  const float* gate_w     = (const float*)d_in[11];
  const float* up_w       = (const float*)d_in[12];
  const float* down_w     = (const float*)d_in[13];
  float* out = (float*)d_out;

  char* ws = (char*)d_ws;
  size_t off = 0;
  auto alloc = [&](size_t bytes) -> void* {
    void* p = ws + off;
    off = (off + bytes + 255) & ~(size_t)255;
    return p;
  };
  // persistent bf16 weights (in_proj padded to 5376 rows)
  u16* wip = (u16*)alloc((size_t)DPROJ_PAD * DMODEL * 2);
  u16* wop = (u16*)alloc((size_t)DMODEL * DINNER * 2);
  u16* wg  = (u16*)alloc((size_t)DFF    * DMODEL * 2);
  u16* wu  = (u16*)alloc((size_t)DFF    * DMODEL * 2);
  u16* wd  = (u16*)alloc((size_t)DMODEL * DFF    * 2);
  // dynamic region; zx..Hv overlaid by split-K partials pK when dead.
  u16*   zx  = (u16*)  alloc((size_t)L_SEQ * DPROJ * 2);
  u16*   xbc = (u16*)  alloc((size_t)L_SEQ * CONVCH * 2);
  float* Sv  = (float*)alloc((size_t)NCHUNK * NHEADS * 4096 * 4);
  float* Hv  = (float*)alloc((size_t)NCHUNK * NHEADS * 4096 * 4);
  float* pK  = (float*)zx;
  float* dtv = (float*)alloc((size_t)L_SEQ * NHEADS * 4);
  float* dAv = (float*)alloc((size_t)L_SEQ * NHEADS * 4);
  float* cum = (float*)alloc((size_t)L_SEQ * NHEADS * 4);
  float* gam = (float*)alloc((size_t)NCHUNK * NHEADS * 4);
  float* yv  = (float*)alloc((size_t)L_SEQ * DINNER * 4);
  float* hres= (float*)alloc((size_t)L_SEQ * DMODEL * 4);
  u16*  gateb= (u16*)  alloc((size_t)L_SEQ * DFF * 2);
  u16*  hslot= (u16*)  alloc((size_t)L_SEQ * DMODEL * 2);
  (void)ws_size; (void)in_sizes; (void)n_in; (void)out_size;

  // 0. weight fp32 -> bf16
  cvt_pad_k<<<(DPROJ_PAD * DMODEL / 8) / 256, 256, 0, stream>>>(in_proj_w, wip);
  cvt_k<<<DMODEL * DINNER / 8 / 256, 256, 0, stream>>>(out_proj_w, wop, DMODEL * DINNER / 8);
  cvt_k<<<DFF * DMODEL / 8 / 256, 256, 0, stream>>>(gate_w, wg, DFF * DMODEL / 8);
  cvt_k<<<DFF * DMODEL / 8 / 256, 256, 0, stream>>>(up_w, wu, DFF * DMODEL / 8);
  cvt_k<<<DMODEL * DFF / 8 / 256, 256, 0, stream>>>(down_w, wd, DMODEL * DFF / 8);

  // 1. input rmsnorm -> bf16
  rmsnorm_k<<<L_SEQ, 256, 0, stream>>>(hs, in_ln_w, hslot);
  // 2. in_proj GEMM (N=5152, padded tiles, store-guarded)
  gemm8<0, 1><<<21 * 8, 512, 0, stream>>>(hslot, wip, zx, nullptr, DPROJ, DMODEL, 21);
  // 3. conv + silu + dt/dA (merged)
  convdt_k<<<3072 + 256, 256, 0, stream>>>(zx, conv_w, conv_b, xbc, dt_bias, A_log, dtv, dAv);
  // 4-6. chunked selective scan
  scan_a<<<dim3(NCHUNK, NHEADS), 256, 0, stream>>>(xbc, dtv, dAv, Dv, yv, Sv, gam, cum);
  scan_b<<<512, 256, 0, stream>>>(Sv, gam, Hv);
  scan_c<<<dim3(NCHUNK, NHEADS), 256, 0, stream>>>(xbc, cum, Hv, yv);
  // 7. gated rmsnorm -> bf16
  gated_rms_k<<<L_SEQ, 256, 0, stream>>>(yv, zx, ssm_w, hslot);
  // 8. out_proj GEMM split-K=4 -> fp32 partials (overlay zx, now dead)
  gemm8<2, 4><<<8 * 8 * 4, 512, 0, stream>>>(hslot, wop, pK, nullptr, DMODEL, DINNER, 8);
  // 9. reduce + hs residual -> hres ; post rmsnorm -> bf16
  red4_rms_k<<<L_SEQ, 256, 0, stream>>>(pK, hs, hres, post_ln_w, hslot);
  // 10. gate GEMM
  gemm8<0, 1><<<32 * 8, 512, 0, stream>>>(hslot, wg, gateb, nullptr, DFF, DMODEL, 32);
  // 11. up GEMM with fused act
  gemm8<3, 1><<<32 * 8, 512, 0, stream>>>(hslot, wu, gateb, gateb, DFF, DMODEL, 32);
  // 12. down GEMM split-K=4
  gemm8<2, 4><<<8 * 8 * 4, 512, 0, stream>>>(gateb, wd, pK, nullptr, DMODEL, DFF, 8);
  // 13. reduce + hres residual -> out
  red4_add_k<<<(L_SEQ * DMODEL / 8) / 256, 256, 0, stream>>>(pK, hres, out);
}